// Round 7
// baseline (322.090 us; speedup 1.0000x reference)
//
#include <hip/hip_runtime.h>
#include <cstdint>

// B=8, T=1024, D=1024, H=16, hd=64
// prep (bf16 convert + weight transpose) -> QKV GEMM -> fused flash attention
// (paired q-tiles share one K/V staging pass; PAIR-MAJOR grid) -> proj GEMM.
// Attn v5: r4's pair-major grid (empirically ~3x less HBM traffic than
// bh-major) + single shared P buffer (40960 B LDS -> 4 blocks/CU) +
// vectorized cached 16B epilogue stores via P_lds transpose.

typedef __attribute__((ext_vector_type(8))) short bf16x8;
typedef __attribute__((ext_vector_type(4))) float f32x4;

__device__ __forceinline__ short f2b(float x) {
  unsigned u = __builtin_bit_cast(unsigned, x);
  u += 0x7fffu + ((u >> 16) & 1u);
  return (short)(u >> 16);
}

__device__ __forceinline__ void gl2lds16(short* l, const short* g) {
  __builtin_amdgcn_global_load_lds(
      (const __attribute__((address_space(1))) void*)g,
      (__attribute__((address_space(3))) void*)l, 16, 0, 0);
}

// ---------------- prep kernels ----------------

__global__ void f32_to_bf16_vec(const float* __restrict__ in,
                                short* __restrict__ outb, int n4) {
  int i = blockIdx.x * 256 + threadIdx.x;
  if (i >= n4) return;
  float4 v = ((const float4*)in)[i];
  short4 o;
  o.x = f2b(v.x); o.y = f2b(v.y); o.z = f2b(v.z); o.w = f2b(v.w);
  ((short4*)outb)[i] = o;
}

// in [R][C] f32 -> out [C][R] bf16
__global__ void transpose_f32_bf16(const float* __restrict__ in,
                                   short* __restrict__ out, int R, int C) {
  __shared__ float tile[32][33];
  int c0 = blockIdx.x * 32, r0 = blockIdx.y * 32;
  int tx = threadIdx.x, ty = threadIdx.y;  // 32 x 8
#pragma unroll
  for (int i = 0; i < 32; i += 8)
    tile[ty + i][tx] = in[(long)(r0 + ty + i) * C + c0 + tx];
  __syncthreads();
#pragma unroll
  for (int i = 0; i < 32; i += 8)
    out[(long)(c0 + ty + i) * R + r0 + tx] = f2b(tile[tx][ty + i]);
}

// ---------------- GEMM: C[M,N] = A[M,K] * Bt[N,K]^T + bias ----------------

template <int EPI>
__global__ __launch_bounds__(256, 3) void gemm_bt(
    const short* __restrict__ A, const short* __restrict__ Bt,
    const float* __restrict__ bias, float* __restrict__ outF,
    short* __restrict__ qh, short* __restrict__ kh, short* __restrict__ vT,
    int M, int N, int K) {
  __shared__ short At[128 * 64];
  __shared__ short Bl[128 * 64];
  const int t = threadIdx.x;
  const int wave = t >> 6, lane = t & 63;
  const int quad = lane >> 4, l15 = lane & 15;
  const int wr = wave >> 1, wc = wave & 1;
  const int m0 = blockIdx.y * 128, n0 = blockIdx.x * 128;

  f32x4 acc[4][4] = {};

  const int srow = t >> 3;
  const int sch0 = t & 7;

  for (int k0 = 0; k0 < K; k0 += 64) {
    __syncthreads();
#pragma unroll
    for (int c = 0; c < 4; ++c) {
      int row = c * 32 + srow;
      int ch = sch0 ^ (row & 7);
      gl2lds16(At + (c * 256 + t) * 8, A + (long)(m0 + row) * K + k0 + ch * 8);
      gl2lds16(Bl + (c * 256 + t) * 8, Bt + (long)(n0 + row) * K + k0 + ch * 8);
    }
    asm volatile("s_waitcnt vmcnt(0)" ::: "memory");
    __syncthreads();

#pragma unroll
    for (int s = 0; s < 2; ++s) {
      const int cx = (s * 4 + quad) ^ (l15 & 7);
      bf16x8 af[4], bfr[4];
#pragma unroll
      for (int i = 0; i < 4; ++i)
        af[i] = *(const bf16x8*)(At + (wr * 64 + i * 16 + l15) * 64 + cx * 8);
#pragma unroll
      for (int j = 0; j < 4; ++j)
        bfr[j] = *(const bf16x8*)(Bl + (wc * 64 + j * 16 + l15) * 64 + cx * 8);
#pragma unroll
      for (int i = 0; i < 4; ++i)
#pragma unroll
        for (int j = 0; j < 4; ++j)
          acc[i][j] = __builtin_amdgcn_mfma_f32_16x16x32_bf16(af[i], bfr[j],
                                                              acc[i][j], 0, 0, 0);
    }
  }

  if (EPI == 1) {
#pragma unroll
    for (int j = 0; j < 4; ++j) {
      int col = n0 + wc * 64 + j * 16 + l15;
      float bv = bias[col];
#pragma unroll
      for (int i = 0; i < 4; ++i)
#pragma unroll
        for (int r = 0; r < 4; ++r) {
          int row = m0 + wr * 64 + i * 16 + quad * 4 + r;
          outF[(long)row * N + col] = acc[i][j][r] + bv;
        }
    }
  } else {
    const int sec = n0 >> 10;
    const int b = m0 >> 10;
#pragma unroll
    for (int j = 0; j < 4; ++j) {
      int col = n0 + wc * 64 + j * 16 + l15;
      float bv = bias[col];
      int d = col & 1023, h = d >> 6, dh = d & 63;
      if (sec == 2) {
        long base = ((long)(b * 16 + h) * 64 + dh) * 1024;
#pragma unroll
        for (int i = 0; i < 4; ++i) {
          int tt0 = (m0 & 1023) + wr * 64 + i * 16 + quad * 4;
          short4 v;
          v.x = f2b(acc[i][j][0] + bv);
          v.y = f2b(acc[i][j][1] + bv);
          v.z = f2b(acc[i][j][2] + bv);
          v.w = f2b(acc[i][j][3] + bv);
          *(short4*)(vT + base + tt0) = v;
        }
      } else {
        short* dst = (sec == 0) ? qh : kh;
        long hbase = ((long)(b * 16 + h) * 1024) * 64 + dh;
#pragma unroll
        for (int i = 0; i < 4; ++i)
#pragma unroll
          for (int r = 0; r < 4; ++r) {
            int tt = (m0 & 1023) + wr * 64 + i * 16 + quad * 4 + r;
            dst[hbase + (long)tt * 64] = f2b(acc[i][j][r] + bv);
          }
      }
    }
  }
}

// ---------------- fused flash attention ----------------
// grid (8 pair, 128 bh) PAIR-MAJOR. Block owns q-tile pair (qt0=p, qt1=15-p);
// one k-loop stages each K/V tile once, both q-tiles consume it. Single P
// buffer (per-wave DS ordering). LDS 40960 B -> 4 blocks/CU.
// Epilogue: o -> P_lds (C-layout->rows) -> cached 16B stores.

__global__ __launch_bounds__(256, 4) void attn_kernel(
    const short* __restrict__ qh, const short* __restrict__ kh,
    const short* __restrict__ vT, short* __restrict__ attout) {
  __shared__ short Kb[2][64 * 64];
  __shared__ short Vb[2][64 * 64];
  __shared__ short P_lds[4][16][64];  // swizzled chunks: ch' = ch ^ (row&7)
  const int pairIdx = blockIdx.x;  // 0..7
  const int bh = blockIdx.y;
  const int t = threadIdx.x;
  const int wave = t >> 6, lane = t & 63, quad = lane >> 4, l15 = lane & 15;
  const short* q_head = qh + (long)bh * 1024 * 64;
  const short* k_head = kh + (long)bh * 1024 * 64;
  const short* v_head = vT + (long)bh * 64 * 1024;
  const int b_ = bh >> 4, h_ = bh & 15;
  const float sl = 0.125f * 1.44269504089f;  // scale * log2(e)

  const int qt0 = pairIdx, qt1 = 15 - pairIdx;  // qt1 > qt0 always
  const int qb0 = qt0 * 64 + wave * 16;
  const int qb1 = qt1 * 64 + wave * 16;

  auto stage = [&](int kt, int buf) {
    const int kk0 = kt * 64;
#pragma unroll
    for (int i = 0; i < 2; ++i) {
      int s = i * 256 + t;
      int row = s >> 3, cg = (s & 7) ^ (row & 7);
      gl2lds16(&Kb[buf][s * 8], k_head + (kk0 + row) * 64 + cg * 8);
    }
#pragma unroll
    for (int i = 0; i < 2; ++i) {
      int s = i * 256 + t;
      int row = s >> 3, cg = (s & 7) ^ (row & 7);
      gl2lds16(&Vb[buf][s * 8], v_head + row * 1024 + kk0 + cg * 8);
    }
  };

  bf16x8 qf0[2], qf1[2];
#pragma unroll
  for (int s = 0; s < 2; ++s) {
    qf0[s] = *(const bf16x8*)(q_head + (qb0 + l15) * 64 + s * 32 + quad * 8);
    qf1[s] = *(const bf16x8*)(q_head + (qb1 + l15) * 64 + s * 32 + quad * 8);
  }

  float l0[4] = {0.f, 0.f, 0.f, 0.f}, l1[4] = {0.f, 0.f, 0.f, 0.f};
  f32x4 o0[4] = {}, o1[4] = {};

  stage(0, 0);
  __syncthreads();

#pragma unroll 1
  for (int kt = 0; kt <= qt1; ++kt) {
    const int buf = kt & 1;
    const short* Kt = Kb[buf];
    const short* Vt = Vb[buf];
    const bool act0 = (kt <= qt0);

    // preload K fragments once; reused by both q-tiles
    bf16x8 kfr[4][2];
#pragma unroll
    for (int jj = 0; jj < 4; ++jj) {
      int row = jj * 16 + l15;
#pragma unroll
      for (int s = 0; s < 2; ++s)
        kfr[jj][s] =
            *(const bf16x8*)(Kt + row * 64 + (((s * 4 + quad) ^ (row & 7)) * 8));
    }

    if (kt < qt1) stage(kt + 1, buf ^ 1);  // overlaps with compute below

    // ---- tile 1 (always active) ----
    {
      f32x4 s1[4] = {};
#pragma unroll
      for (int jj = 0; jj < 4; ++jj) {
        s1[jj] =
            __builtin_amdgcn_mfma_f32_16x16x32_bf16(qf1[0], kfr[jj][0], s1[jj], 0, 0, 0);
        s1[jj] =
            __builtin_amdgcn_mfma_f32_16x16x32_bf16(qf1[1], kfr[jj][1], s1[jj], 0, 0, 0);
      }
      const bool diag1 = (kt == qt1);
#pragma unroll
      for (int jj = 0; jj < 4; ++jj) {
        int key = kt * 64 + jj * 16 + l15;
        int ch = jj * 2 + (l15 >> 3), co = l15 & 7;
#pragma unroll
        for (int r = 0; r < 4; ++r) {
          int row = quad * 4 + r;
          float sv = s1[jj][r] * sl;
          if (diag1 && key > qb1 + row) sv = -1e30f;
          float e = __builtin_amdgcn_exp2f(sv);
          l1[r] += e;
          P_lds[wave][row][(ch ^ (row & 7)) * 8 + co] = f2b(e);
        }
      }
      asm volatile("s_waitcnt lgkmcnt(0)" ::: "memory");
      bf16x8 pf[2];
#pragma unroll
      for (int s = 0; s < 2; ++s)
        pf[s] = *(const bf16x8*)(&P_lds[wave][l15][((s * 4 + quad) ^ (l15 & 7)) * 8]);
#pragma unroll
      for (int dj = 0; dj < 4; ++dj) {
        int row = dj * 16 + l15;
#pragma unroll
        for (int s = 0; s < 2; ++s) {
          bf16x8 vf =
              *(const bf16x8*)(Vt + row * 64 + (((s * 4 + quad) ^ (row & 7)) * 8));
          o1[dj] = __builtin_amdgcn_mfma_f32_16x16x32_bf16(pf[s], vf, o1[dj], 0, 0, 0);
        }
      }
    }

    // ---- tile 0 (active while kt <= qt0) ----
    if (act0) {
      f32x4 s0[4] = {};
#pragma unroll
      for (int jj = 0; jj < 4; ++jj) {
        s0[jj] =
            __builtin_amdgcn_mfma_f32_16x16x32_bf16(qf0[0], kfr[jj][0], s0[jj], 0, 0, 0);
        s0[jj] =
            __builtin_amdgcn_mfma_f32_16x16x32_bf16(qf0[1], kfr[jj][1], s0[jj], 0, 0, 0);
      }
      const bool diag0 = (kt == qt0);
#pragma unroll
      for (int jj = 0; jj < 4; ++jj) {
        int key = kt * 64 + jj * 16 + l15;
        int ch = jj * 2 + (l15 >> 3), co = l15 & 7;
#pragma unroll
        for (int r = 0; r < 4; ++r) {
          int row = quad * 4 + r;
          float sv = s0[jj][r] * sl;
          if (diag0 && key > qb0 + row) sv = -1e30f;
          float e = __builtin_amdgcn_exp2f(sv);
          l0[r] += e;
          P_lds[wave][row][(ch ^ (row & 7)) * 8 + co] = f2b(e);
        }
      }
      asm volatile("s_waitcnt lgkmcnt(0)" ::: "memory");
      bf16x8 pf[2];
#pragma unroll
      for (int s = 0; s < 2; ++s)
        pf[s] = *(const bf16x8*)(&P_lds[wave][l15][((s * 4 + quad) ^ (l15 & 7)) * 8]);
#pragma unroll
      for (int dj = 0; dj < 4; ++dj) {
        int row = dj * 16 + l15;
#pragma unroll
        for (int s = 0; s < 2; ++s) {
          bf16x8 vf =
              *(const bf16x8*)(Vt + row * 64 + (((s * 4 + quad) ^ (row & 7)) * 8));
          o0[dj] = __builtin_amdgcn_mfma_f32_16x16x32_bf16(pf[s], vf, o0[dj], 0, 0, 0);
        }
      }
    }
    __syncthreads();  // releases buf for re-stage; drains prefetch vmcnt
  }

  // deferred l reductions
#pragma unroll
  for (int off = 1; off < 16; off <<= 1)
#pragma unroll
    for (int r = 0; r < 4; ++r) {
      l0[r] += __shfl_xor(l0[r], off);
      l1[r] += __shfl_xor(l1[r], off);
    }
  float inv0[4], inv1[4];
#pragma unroll
  for (int r = 0; r < 4; ++r) {
    inv0[r] = __builtin_amdgcn_rcpf(l0[r]);
    inv1[r] = __builtin_amdgcn_rcpf(l1[r]);
  }

  // epilogue: C-layout -> rows via P_lds, then cached 16B stores.
  // (per-wave region + in-order DS pipe -> no barrier needed)
  const int erow = lane >> 3, ech = lane & 7;
#pragma unroll
  for (int tile = 0; tile < 2; ++tile) {
    const f32x4* o = tile ? o1 : o0;
    const float* inv = tile ? inv1 : inv0;
    const int qb = tile ? qb1 : qb0;
#pragma unroll
    for (int dj = 0; dj < 4; ++dj) {
      int ch = dj * 2 + (l15 >> 3), co = l15 & 7;
#pragma unroll
      for (int r = 0; r < 4; ++r) {
        int row = quad * 4 + r;
        P_lds[wave][row][(ch ^ (row & 7)) * 8 + co] = f2b(o[dj][r] * inv[r]);
      }
    }
    asm volatile("s_waitcnt lgkmcnt(0)" ::: "memory");
#pragma unroll
    for (int pass = 0; pass < 2; ++pass) {
      int row = pass * 8 + erow;
      bf16x8 v = *(const bf16x8*)(&P_lds[wave][row][(ech ^ (row & 7)) * 8]);
      long g = (long)b_ * 1024 + qb + row;
      *(bf16x8*)(attout + g * 1024 + h_ * 64 + ech * 8) = v;
    }
    asm volatile("s_waitcnt lgkmcnt(0)" ::: "memory");  // reads done before next tile's writes
  }
}

// ---------------- launch ----------------

extern "C" void kernel_launch(void* const* d_in, const int* in_sizes, int n_in,
                              void* d_out, int out_size, void* d_ws,
                              size_t ws_size, hipStream_t stream) {
  const float* x = (const float*)d_in[0];
  const float* W_attn = (const float*)d_in[2];
  const float* b_attn = (const float*)d_in[3];
  const float* W_proj = (const float*)d_in[4];
  const float* b_proj = (const float*)d_in[5];
  float* out = (float*)d_out;

  char* ws = (char*)d_ws;
  const size_t MB = 1u << 20;
  short* xb = (short*)(ws);              // 16 MB [0,16)
  short* WaT = (short*)(ws + 16 * MB);   // 6 MB  [16,22)
  short* WpT = (short*)(ws + 22 * MB);   // 2 MB  [22,24)
  short* qh = (short*)(ws + 24 * MB);    // 16 MB [24,40)
  short* kh = (short*)(ws + 40 * MB);    // 16 MB [40,56)
  short* vT = (short*)(ws + 56 * MB);    // 16 MB [56,72)
  short* attout = xb;                    // reuse x-bf16 region

  f32_to_bf16_vec<<<8192, 256, 0, stream>>>(x, xb, 2097152);
  transpose_f32_bf16<<<dim3(3072 / 32, 1024 / 32), dim3(32, 8), 0, stream>>>(
      W_attn, WaT, 1024, 3072);
  transpose_f32_bf16<<<dim3(1024 / 32, 1024 / 32), dim3(32, 8), 0, stream>>>(
      W_proj, WpT, 1024, 1024);
  gemm_bt<0><<<dim3(3072 / 128, 8192 / 128), 256, 0, stream>>>(
      xb, WaT, b_attn, nullptr, qh, kh, vT, 8192, 3072, 1024);
  attn_kernel<<<dim3(8, 128), 256, 0, stream>>>(qh, kh, vT, attout);
  gemm_bt<1><<<dim3(1024 / 128, 8192 / 128), 256, 0, stream>>>(
      attout, WpT, b_proj, out, nullptr, nullptr, nullptr, 8192, 1024, 1024);
}

// Round 8
// 230.482 us; speedup vs baseline: 1.3975x; 1.3975x over previous
//
#include <hip/hip_runtime.h>
#include <cstdint>

// B=8, T=1024, D=1024, H=16, hd=64
// prep (bf16 convert + weight transpose) -> QKV GEMM -> fused flash attention
// (4 q-tiles/block share one K/V staging pass) -> proj GEMM.
// Attn v6: __launch_bounds__(256,2) -> 256 regs/wave (r5-r7 regressions were
// register spill at the 4-waves/EU 128-reg budget: symmetric ~150MB
// FETCH/WRITE scratch traffic, bit-exact-repeatable WRITE_SIZE).
// 4 q-tiles {p,7-p,8+p,15-p} per block: balanced (34 tile-iters each),
// 4x MFMA per staged K/V byte, 4 independent chains per wave.

typedef __attribute__((ext_vector_type(8))) short bf16x8;
typedef __attribute__((ext_vector_type(4))) float f32x4;

__device__ __forceinline__ short f2b(float x) {
  unsigned u = __builtin_bit_cast(unsigned, x);
  u += 0x7fffu + ((u >> 16) & 1u);
  return (short)(u >> 16);
}

__device__ __forceinline__ void gl2lds16(short* l, const short* g) {
  __builtin_amdgcn_global_load_lds(
      (const __attribute__((address_space(1))) void*)g,
      (__attribute__((address_space(3))) void*)l, 16, 0, 0);
}

// ---------------- prep kernels ----------------

__global__ void f32_to_bf16_vec(const float* __restrict__ in,
                                short* __restrict__ outb, int n4) {
  int i = blockIdx.x * 256 + threadIdx.x;
  if (i >= n4) return;
  float4 v = ((const float4*)in)[i];
  short4 o;
  o.x = f2b(v.x); o.y = f2b(v.y); o.z = f2b(v.z); o.w = f2b(v.w);
  ((short4*)outb)[i] = o;
}

// in [R][C] f32 -> out [C][R] bf16
__global__ void transpose_f32_bf16(const float* __restrict__ in,
                                   short* __restrict__ out, int R, int C) {
  __shared__ float tile[32][33];
  int c0 = blockIdx.x * 32, r0 = blockIdx.y * 32;
  int tx = threadIdx.x, ty = threadIdx.y;  // 32 x 8
#pragma unroll
  for (int i = 0; i < 32; i += 8)
    tile[ty + i][tx] = in[(long)(r0 + ty + i) * C + c0 + tx];
  __syncthreads();
#pragma unroll
  for (int i = 0; i < 32; i += 8)
    out[(long)(c0 + ty + i) * R + r0 + tx] = f2b(tile[tx][ty + i]);
}

// ---------------- GEMM: C[M,N] = A[M,K] * Bt[N,K]^T + bias ----------------

template <int EPI>
__global__ __launch_bounds__(256, 3) void gemm_bt(
    const short* __restrict__ A, const short* __restrict__ Bt,
    const float* __restrict__ bias, float* __restrict__ outF,
    short* __restrict__ qh, short* __restrict__ kh, short* __restrict__ vT,
    int M, int N, int K) {
  __shared__ short At[128 * 64];
  __shared__ short Bl[128 * 64];
  const int t = threadIdx.x;
  const int wave = t >> 6, lane = t & 63;
  const int quad = lane >> 4, l15 = lane & 15;
  const int wr = wave >> 1, wc = wave & 1;
  const int m0 = blockIdx.y * 128, n0 = blockIdx.x * 128;

  f32x4 acc[4][4] = {};

  const int srow = t >> 3;
  const int sch0 = t & 7;

  for (int k0 = 0; k0 < K; k0 += 64) {
    __syncthreads();
#pragma unroll
    for (int c = 0; c < 4; ++c) {
      int row = c * 32 + srow;
      int ch = sch0 ^ (row & 7);
      gl2lds16(At + (c * 256 + t) * 8, A + (long)(m0 + row) * K + k0 + ch * 8);
      gl2lds16(Bl + (c * 256 + t) * 8, Bt + (long)(n0 + row) * K + k0 + ch * 8);
    }
    asm volatile("s_waitcnt vmcnt(0)" ::: "memory");
    __syncthreads();

#pragma unroll
    for (int s = 0; s < 2; ++s) {
      const int cx = (s * 4 + quad) ^ (l15 & 7);
      bf16x8 af[4], bfr[4];
#pragma unroll
      for (int i = 0; i < 4; ++i)
        af[i] = *(const bf16x8*)(At + (wr * 64 + i * 16 + l15) * 64 + cx * 8);
#pragma unroll
      for (int j = 0; j < 4; ++j)
        bfr[j] = *(const bf16x8*)(Bl + (wc * 64 + j * 16 + l15) * 64 + cx * 8);
#pragma unroll
      for (int i = 0; i < 4; ++i)
#pragma unroll
        for (int j = 0; j < 4; ++j)
          acc[i][j] = __builtin_amdgcn_mfma_f32_16x16x32_bf16(af[i], bfr[j],
                                                              acc[i][j], 0, 0, 0);
    }
  }

  if (EPI == 1) {
#pragma unroll
    for (int j = 0; j < 4; ++j) {
      int col = n0 + wc * 64 + j * 16 + l15;
      float bv = bias[col];
#pragma unroll
      for (int i = 0; i < 4; ++i)
#pragma unroll
        for (int r = 0; r < 4; ++r) {
          int row = m0 + wr * 64 + i * 16 + quad * 4 + r;
          outF[(long)row * N + col] = acc[i][j][r] + bv;
        }
    }
  } else {
    const int sec = n0 >> 10;
    const int b = m0 >> 10;
#pragma unroll
    for (int j = 0; j < 4; ++j) {
      int col = n0 + wc * 64 + j * 16 + l15;
      float bv = bias[col];
      int d = col & 1023, h = d >> 6, dh = d & 63;
      if (sec == 2) {
        long base = ((long)(b * 16 + h) * 64 + dh) * 1024;
#pragma unroll
        for (int i = 0; i < 4; ++i) {
          int tt0 = (m0 & 1023) + wr * 64 + i * 16 + quad * 4;
          short4 v;
          v.x = f2b(acc[i][j][0] + bv);
          v.y = f2b(acc[i][j][1] + bv);
          v.z = f2b(acc[i][j][2] + bv);
          v.w = f2b(acc[i][j][3] + bv);
          *(short4*)(vT + base + tt0) = v;
        }
      } else {
        short* dst = (sec == 0) ? qh : kh;
        long hbase = ((long)(b * 16 + h) * 1024) * 64 + dh;
#pragma unroll
        for (int i = 0; i < 4; ++i)
#pragma unroll
          for (int r = 0; r < 4; ++r) {
            int tt = (m0 & 1023) + wr * 64 + i * 16 + quad * 4 + r;
            dst[hbase + (long)tt * 64] = f2b(acc[i][j][r] + bv);
          }
      }
    }
  }
}

// ---------------- fused flash attention ----------------
// grid (4, 128). Block owns q-tiles {p, 7-p, 8+p, 15-p} (ascending, balanced:
// 34 active tile-iters for every p). One k-loop to qt[3]; stage each K/V tile
// once, preload K+V fragments once, apply to all active tiles.
// Single P buffer (per-wave in-order DS). LDS 40960 B. 2 blocks/CU
// (register-limited; 256 regs/wave -> no spill at ~220 live regs).

__global__ __launch_bounds__(256, 2) void attn_kernel(
    const short* __restrict__ qh, const short* __restrict__ kh,
    const short* __restrict__ vT, short* __restrict__ attout) {
  __shared__ short Kb[2][64 * 64];
  __shared__ short Vb[2][64 * 64];
  __shared__ short P_lds[4][16][64];  // swizzled chunks: ch' = ch ^ (row&7)
  const int p = blockIdx.x;  // 0..3
  const int bh = blockIdx.y;
  const int t = threadIdx.x;
  const int wave = t >> 6, lane = t & 63, quad = lane >> 4, l15 = lane & 15;
  const short* q_head = qh + (long)bh * 1024 * 64;
  const short* k_head = kh + (long)bh * 1024 * 64;
  const short* v_head = vT + (long)bh * 64 * 1024;
  const int b_ = bh >> 4, h_ = bh & 15;
  const float sl = 0.125f * 1.44269504089f;  // scale * log2(e)

  const int qt[4] = {p, 7 - p, 8 + p, 15 - p};  // ascending

  auto stage = [&](int kt, int buf) {
    const int kk0 = kt * 64;
#pragma unroll
    for (int i = 0; i < 2; ++i) {
      int s = i * 256 + t;
      int row = s >> 3, cg = (s & 7) ^ (row & 7);
      gl2lds16(&Kb[buf][s * 8], k_head + (kk0 + row) * 64 + cg * 8);
    }
#pragma unroll
    for (int i = 0; i < 2; ++i) {
      int s = i * 256 + t;
      int row = s >> 3, cg = (s & 7) ^ (row & 7);
      gl2lds16(&Vb[buf][s * 8], v_head + row * 1024 + kk0 + cg * 8);
    }
  };

  bf16x8 qf[4][2];
#pragma unroll
  for (int i = 0; i < 4; ++i) {
    int qb = qt[i] * 64 + wave * 16;
#pragma unroll
    for (int s = 0; s < 2; ++s)
      qf[i][s] = *(const bf16x8*)(q_head + (qb + l15) * 64 + s * 32 + quad * 8);
  }

  float l[4][4] = {};
  f32x4 o[4][4] = {};

  stage(0, 0);
  __syncthreads();

  const int nkt = qt[3] + 1;  // 16 - p

#pragma unroll 1
  for (int kt = 0; kt < nkt; ++kt) {
    const int buf = kt & 1;
    const short* Kt = Kb[buf];
    const short* Vt = Vb[buf];

    // preload K and V fragments once; shared by all active q-tiles
    bf16x8 kfr[4][2], vfr[4][2];
#pragma unroll
    for (int jj = 0; jj < 4; ++jj) {
      int row = jj * 16 + l15;
#pragma unroll
      for (int s = 0; s < 2; ++s) {
        int off = ((s * 4 + quad) ^ (row & 7)) * 8;
        kfr[jj][s] = *(const bf16x8*)(Kt + row * 64 + off);
        vfr[jj][s] = *(const bf16x8*)(Vt + row * 64 + off);
      }
    }

    if (kt + 1 < nkt) stage(kt + 1, buf ^ 1);  // overlaps with compute below

#pragma unroll
    for (int i = 0; i < 4; ++i) {
      if (kt <= qt[i]) {
        f32x4 s4[4] = {};
#pragma unroll
        for (int jj = 0; jj < 4; ++jj) {
          s4[jj] = __builtin_amdgcn_mfma_f32_16x16x32_bf16(qf[i][0], kfr[jj][0],
                                                           s4[jj], 0, 0, 0);
          s4[jj] = __builtin_amdgcn_mfma_f32_16x16x32_bf16(qf[i][1], kfr[jj][1],
                                                           s4[jj], 0, 0, 0);
        }
        const bool diag = (kt == qt[i]);
        const int qb = qt[i] * 64 + wave * 16;
#pragma unroll
        for (int jj = 0; jj < 4; ++jj) {
          int key = kt * 64 + jj * 16 + l15;
          int ch = jj * 2 + (l15 >> 3), co = l15 & 7;
#pragma unroll
          for (int r = 0; r < 4; ++r) {
            int row = quad * 4 + r;
            float sv = s4[jj][r] * sl;
            if (diag && key > qb + row) sv = -1e30f;
            float e = __builtin_amdgcn_exp2f(sv);
            l[i][r] += e;
            P_lds[wave][row][(ch ^ (row & 7)) * 8 + co] = f2b(e);
          }
        }
        asm volatile("s_waitcnt lgkmcnt(0)" ::: "memory");
        bf16x8 pf[2];
#pragma unroll
        for (int s = 0; s < 2; ++s)
          pf[s] =
              *(const bf16x8*)(&P_lds[wave][l15][((s * 4 + quad) ^ (l15 & 7)) * 8]);
#pragma unroll
        for (int dj = 0; dj < 4; ++dj) {
          o[i][dj] = __builtin_amdgcn_mfma_f32_16x16x32_bf16(pf[0], vfr[dj][0],
                                                             o[i][dj], 0, 0, 0);
          o[i][dj] = __builtin_amdgcn_mfma_f32_16x16x32_bf16(pf[1], vfr[dj][1],
                                                             o[i][dj], 0, 0, 0);
        }
      }
    }
    __syncthreads();  // releases buf for re-stage; drains prefetch vmcnt
  }

  // deferred l reductions
#pragma unroll
  for (int off = 1; off < 16; off <<= 1)
#pragma unroll
    for (int i = 0; i < 4; ++i)
#pragma unroll
      for (int r = 0; r < 4; ++r) l[i][r] += __shfl_xor(l[i][r], off);

  // epilogue: per tile, C-layout -> rows via P_lds, then cached 16B stores.
  const int erow = lane >> 3, ech = lane & 7;
#pragma unroll
  for (int i = 0; i < 4; ++i) {
    float inv[4];
#pragma unroll
    for (int r = 0; r < 4; ++r) inv[r] = __builtin_amdgcn_rcpf(l[i][r]);
    const int qb = qt[i] * 64 + wave * 16;
#pragma unroll
    for (int dj = 0; dj < 4; ++dj) {
      int ch = dj * 2 + (l15 >> 3), co = l15 & 7;
#pragma unroll
      for (int r = 0; r < 4; ++r) {
        int row = quad * 4 + r;
        P_lds[wave][row][(ch ^ (row & 7)) * 8 + co] = f2b(o[i][dj][r] * inv[r]);
      }
    }
    asm volatile("s_waitcnt lgkmcnt(0)" ::: "memory");
#pragma unroll
    for (int pass = 0; pass < 2; ++pass) {
      int row = pass * 8 + erow;
      bf16x8 v = *(const bf16x8*)(&P_lds[wave][row][(ech ^ (row & 7)) * 8]);
      long g = (long)b_ * 1024 + qb + row;
      *(bf16x8*)(attout + g * 1024 + h_ * 64 + ech * 8) = v;
    }
    asm volatile("s_waitcnt lgkmcnt(0)" ::: "memory");  // reads before next writes
  }
}

// ---------------- launch ----------------

extern "C" void kernel_launch(void* const* d_in, const int* in_sizes, int n_in,
                              void* d_out, int out_size, void* d_ws,
                              size_t ws_size, hipStream_t stream) {
  const float* x = (const float*)d_in[0];
  const float* W_attn = (const float*)d_in[2];
  const float* b_attn = (const float*)d_in[3];
  const float* W_proj = (const float*)d_in[4];
  const float* b_proj = (const float*)d_in[5];
  float* out = (float*)d_out;

  char* ws = (char*)d_ws;
  const size_t MB = 1u << 20;
  short* xb = (short*)(ws);              // 16 MB [0,16)
  short* WaT = (short*)(ws + 16 * MB);   // 6 MB  [16,22)
  short* WpT = (short*)(ws + 22 * MB);   // 2 MB  [22,24)
  short* qh = (short*)(ws + 24 * MB);    // 16 MB [24,40)
  short* kh = (short*)(ws + 40 * MB);    // 16 MB [40,56)
  short* vT = (short*)(ws + 56 * MB);    // 16 MB [56,72)
  short* attout = xb;                    // reuse x-bf16 region

  f32_to_bf16_vec<<<8192, 256, 0, stream>>>(x, xb, 2097152);
  transpose_f32_bf16<<<dim3(3072 / 32, 1024 / 32), dim3(32, 8), 0, stream>>>(
      W_attn, WaT, 1024, 3072);
  transpose_f32_bf16<<<dim3(1024 / 32, 1024 / 32), dim3(32, 8), 0, stream>>>(
      W_proj, WpT, 1024, 1024);
  gemm_bt<0><<<dim3(3072 / 128, 8192 / 128), 256, 0, stream>>>(
      xb, WaT, b_attn, nullptr, qh, kh, vT, 8192, 3072, 1024);
  attn_kernel<<<dim3(4, 128), 256, 0, stream>>>(qh, kh, vT, attout);
  gemm_bt<1><<<dim3(1024 / 128, 8192 / 128), 256, 0, stream>>>(
      attout, WpT, b_proj, out, nullptr, nullptr, nullptr, 8192, 1024, 1024);
}